// Round 9
// baseline (309.798 us; speedup 1.0000x reference)
//
#include <hip/hip_runtime.h>
#include <math.h>

#define SEQ_LEN   720
#define IN_LEN    360
#define PRED_LEN  336
#define CHANNELS  862
#define RANK      32
#define BATCH     256

typedef _Float16 h2 __attribute__((ext_vector_type(2)));

// ws float offsets
#define WS_WP    0        // Wp  [360][32] fp32
#define WS_VT    11520    // Vt  [336][32] fp32
#define WS_CVEC  22272    // cvec[336] fp32
#define WS_WH    22608    // packed W: u32[180*32]  word[np*32+r] = (W[2np][r], W[2np+1][r])
#define WS_VH    28368    // packed V: u32[336*16]  word[n*16+q]  = (V[n][2q],  V[n][2q+1])

__device__ __forceinline__ float fdot2w(h2 a, h2 b, float c) {
#if __has_builtin(__builtin_amdgcn_fdot2)
    return __builtin_amdgcn_fdot2(a, b, c, false);
#else
    return fmaf((float)a[0], (float)b[0], fmaf((float)a[1], (float)b[1], c));
#endif
}
__device__ __forceinline__ h2 pkrtz(float a, float b) {
    return __builtin_bit_cast(h2, __builtin_amdgcn_cvt_pkrtz(a, b));
}
#define BC(u) __builtin_bit_cast(h2, (u))

// ---------------- prep: fold DCT/IDCT into Wp, Vt, cvec ----------------------
__global__ __launch_bounds__(256) void k_prep(const float* __restrict__ A,
                                              const float* __restrict__ B,
                                              const float* __restrict__ bias,
                                              float* __restrict__ Wp,
                                              float* __restrict__ Vt,
                                              float* __restrict__ cvec) {
    __shared__ float sbuf[IN_LEN * RANK];
    int blk = blockIdx.x;
    if (blk < 45) {
        for (int i = threadIdx.x; i < IN_LEN * RANK; i += 256) sbuf[i] = A[i];
        __syncthreads();
        int idx = blk * 256 + threadIdx.x;           // 45*256 == 11520
        int n = idx >> 5, r = idx & 31;
        int step = 2 * n + 1, m = 0;                 // k*(2n+1) mod 1440
        float sum = 0.f;
        for (int k = 0; k < IN_LEN; ++k) {
            float coef = (k == 0) ? 0.05270462766947299f    // 1/sqrt(360)
                                  : 0.07453559924999299f;   // 2/sqrt(720)
            float d = coef * cospif((float)m * (1.0f / 720.0f));
            sum = fmaf(d, sbuf[k * RANK + r], sum);
            m += step; if (m >= 1440) m -= 1440;
        }
        Wp[idx] = sum * 0.0019641855032960957f;      // (1/sqrt2)/360
    } else if (blk < 87) {
        for (int i = threadIdx.x; i < PRED_LEN * RANK; i += 256) {
            int r = i / PRED_LEN, k = i - r * PRED_LEN;
            sbuf[k * RANK + r] = B[i];               // B^T -> [k][r]
        }
        __syncthreads();
        int idx = (blk - 45) * 256 + threadIdx.x;    // 42*256 == 10752
        int n = idx >> 5, r = idx & 31;
        int step = 2 * n + 1, m = 0;                 // k*(2n+1) mod 1344
        float sum = 0.f;
        for (int k = 0; k < PRED_LEN; ++k) {
            float mk = cospif((float)m * (1.0f / 672.0f));
            if (k == 0) mk *= 0.5f;
            sum = fmaf(mk, sbuf[k * RANK + r], sum);
            m += step; if (m >= 1344) m -= 1344;
        }
        Vt[idx] = sum * (1.0f / 336.0f);
    } else {
        int n = (blk - 87) * 256 + threadIdx.x;
        if (n < PRED_LEN) {
            int step = 2 * n + 1, m = 0;
            float sum = 0.f;
            for (int k = 0; k < PRED_LEN; ++k) {
                float mk = cospif((float)m * (1.0f / 672.0f));
                if (k == 0) mk *= 0.5f;
                sum = fmaf(mk, bias[k], sum);
                m += step; if (m >= 1344) m -= 1344;
            }
            cvec[n] = sum * (1.0f / 336.0f);
        }
    }
}

// ---------------- pack fp32 weights into paired fp16 -------------------------
__global__ __launch_bounds__(256) void k_pack(const float* __restrict__ Wp,
                                              const float* __restrict__ Vt,
                                              unsigned* __restrict__ Wh,
                                              unsigned* __restrict__ Vh) {
    int idx = blockIdx.x * 256 + threadIdx.x;        // 44*256 = 11264 >= 11136
    if (idx < 5760) {
        int np = idx >> 5, r = idx & 31;
        h2 v = pkrtz(Wp[(2 * np) * RANK + r], Wp[(2 * np + 1) * RANK + r]);
        Wh[idx] = __builtin_bit_cast(unsigned, v);
    } else if (idx < 5760 + 5376) {
        int j = idx - 5760;
        int n = j >> 4, q = j & 15;
        h2 v = pkrtz(Vt[n * RANK + 2 * q], Vt[n * RANK + 2 * q + 1]);
        Vh[j] = __builtin_bit_cast(unsigned, v);
    }
}

// ---------------- fused main kernel ------------------------------------------
// cpt=1, 256 thr, grid (4, BATCH) = 1024 blocks -> 4 blocks/CU, 16 waves/CU,
// 4 waves/SIMD for latency hiding. ~80 VGPR (no-spill regime). fp16 paired
// weights in LDS (broadcast ds_read_b128), fdot2 MACs, fp32 mean path.
__global__ __launch_bounds__(256) void k_main(const float* __restrict__ x,
                                              const float* __restrict__ A,
                                              const unsigned* __restrict__ Wh,
                                              const unsigned* __restrict__ Vh,
                                              const float* __restrict__ cvec,
                                              float* __restrict__ out) {
    __shared__ uint4 lds4[1440];                     // 23040 B (ph1: W; ph2: V+cvec)
    unsigned* ldsu = (unsigned*)lds4;
    const int tid = threadIdx.x;
    const int b = blockIdx.y;
    const int c = blockIdx.x * 256 + tid;
    const bool active = (c < CHANNELS);

    // ---- stage packed W ----
    {
        const uint4* s = (const uint4*)Wh;
        for (int i = tid; i < 1440; i += 256) lds4[i] = s[i];
    }
    __syncthreads();

    float acc[RANK];
    #pragma unroll
    for (int r = 0; r < RANK; ++r) acc[r] = 0.f;
    float S = 0.f, mean = 0.f;
    h2 th[16];

    if (active) {
        const float* xp = x + (size_t)b * (SEQ_LEN * CHANNELS) + c;

        // chunk bd = 8 x-rows = 4 n = 2 np (np = 2bd, 2bd+1)
        float bufA[8], bufB[8];
        #define LOADB(BUF, BD) { const float* p_ = xp + (size_t)(BD) * (8 * CHANNELS); \
            _Pragma("unroll") \
            for (int j_ = 0; j_ < 8; ++j_) BUF[j_] = p_[j_ * CHANNELS]; }

        // one n-pair: rows BUF[4S..4S+3]; W words at wr[8S..8S+7]
        #define NPBODY(BUF, S_) { \
            float pe = BUF[4*S_+0] + BUF[4*S_+1]; \
            float po = BUF[4*S_+2] + BUF[4*S_+3]; \
            S += pe + po; \
            h2 P = pkrtz(pe, po); \
            _Pragma("unroll") \
            for (int q_ = 0; q_ < 8; ++q_) { \
                uint4 wv = wr[8*S_ + q_]; \
                acc[4*q_+0] = fdot2w(P, BC(wv.x), acc[4*q_+0]); \
                acc[4*q_+1] = fdot2w(P, BC(wv.y), acc[4*q_+1]); \
                acc[4*q_+2] = fdot2w(P, BC(wv.z), acc[4*q_+2]); \
                acc[4*q_+3] = fdot2w(P, BC(wv.w), acc[4*q_+3]); \
            } }

        #define BODY(BUF, BD) { const uint4* wr = lds4 + 16 * (BD); \
            NPBODY(BUF, 0); NPBODY(BUF, 1); }

        LOADB(bufA, 0)
        for (int it = 0; it < 45; ++it) {
            LOADB(bufB, 2 * it + 1)
            BODY(bufA, 2 * it)
            if (it < 44) LOADB(bufA, 2 * it + 2)
            BODY(bufB, 2 * it + 1)
        }
        #undef BODY
        #undef NPBODY
        #undef LOADB

        // finalize: csw[r] = A[0][r]/sqrt(720);  t -= (S/360)*csw  (fp32 exact)
        const float k360 = (1.0f / 360.0f) * 0.037267799624996496f;
        float g = -S * k360;
        #pragma unroll
        for (int q = 0; q < 8; ++q) {
            float4 a4 = ((const float4*)A)[q];       // A[0][0..31], uniform, L2-hot
            acc[4*q+0] = fmaf(g, a4.x, acc[4*q+0]);
            acc[4*q+1] = fmaf(g, a4.y, acc[4*q+1]);
            acc[4*q+2] = fmaf(g, a4.z, acc[4*q+2]);
            acc[4*q+3] = fmaf(g, a4.w, acc[4*q+3]);
        }
        mean = S * (1.0f / 720.0f);

        // pack t to fp16 pairs for phase 2
        #pragma unroll
        for (int u = 0; u < 16; ++u) th[u] = pkrtz(acc[2*u], acc[2*u+1]);
    }
    __syncthreads();                                 // phase-1 LDS reads done

    // ---- re-stage: packed V + fp32 cvec ----
    {
        const uint4* s = (const uint4*)Vh;
        for (int i = tid; i < 1344; i += 256) lds4[i] = s[i];
        for (int i = tid; i < PRED_LEN; i += 256)
            ldsu[5376 + i] = __float_as_uint(cvec[i]);
    }
    __syncthreads();

    // ---- phase 2: out[b][n][c] = t . V[n][:] + cvec[n] + mean ----
    if (active) {
        float* op = out + (size_t)b * (PRED_LEN * CHANNELS) + c;
        #pragma unroll 2
        for (int n = 0; n < PRED_LEN; ++n) {
            const uint4* vr = lds4 + n * 4;
            float oA = 0.f, oB = 0.f;
            #pragma unroll
            for (int q = 0; q < 4; ++q) {
                uint4 v = vr[q];
                oA = fdot2w(th[4*q+0], BC(v.x), oA);
                oB = fdot2w(th[4*q+1], BC(v.y), oB);
                oA = fdot2w(th[4*q+2], BC(v.z), oA);
                oB = fdot2w(th[4*q+3], BC(v.w), oB);
            }
            float cvn = __uint_as_float(ldsu[5376 + n]);
            *op = (oA + oB) + cvn + mean;
            op += CHANNELS;
        }
    }
}

// ---------------- launcher ---------------------------------------------------

extern "C" void kernel_launch(void* const* d_in, const int* in_sizes, int n_in,
                              void* d_out, int out_size, void* d_ws, size_t ws_size,
                              hipStream_t stream) {
    (void)in_sizes; (void)n_in; (void)out_size; (void)ws_size;
    const float* x    = (const float*)d_in[0];
    const float* A    = (const float*)d_in[1];
    const float* B    = (const float*)d_in[2];
    const float* bias = (const float*)d_in[3];
    float* out = (float*)d_out;
    float* ws  = (float*)d_ws;

    float*    Wp   = ws + WS_WP;
    float*    Vt   = ws + WS_VT;
    float*    cvec = ws + WS_CVEC;
    unsigned* Wh   = (unsigned*)(ws + WS_WH);
    unsigned* Vh   = (unsigned*)(ws + WS_VH);

    k_prep<<<dim3(89), dim3(256), 0, stream>>>(A, B, bias, Wp, Vt, cvec);
    k_pack<<<dim3(44), dim3(256), 0, stream>>>(Wp, Vt, Wh, Vh);
    k_main<<<dim3(4, BATCH), dim3(256), 0, stream>>>(x, A, Wh, Vh, cvec, out);
}

// Round 10
// 271.597 us; speedup vs baseline: 1.1407x; 1.1407x over previous
//
#include <hip/hip_runtime.h>
#include <math.h>

#define SEQ_LEN   720
#define IN_LEN    360
#define PRED_LEN  336
#define CHANNELS  862
#define RANK      32
#define BATCH     256

typedef _Float16 h2 __attribute__((ext_vector_type(2)));

// ws float offsets
#define WS_WP    0        // Wp  [360][32] fp32
#define WS_VT    11520    // Vt  [336][32] fp32
#define WS_CVEC  22272    // cvec[336] fp32
#define WS_WH    22608    // packed W: u32[360*16]  word[n*16+j] = (W[n][2j], W[n][2j+1])
#define WS_VH    28368    // packed V: u32[336*16]  word[n*16+j] = (V[n][2j], V[n][2j+1])

// LDS u32 offsets (total 40848 u32 = 163392 B <= 163840)
#define L_EX     0        // [432 slots][68 u32]  (acc h2[4][16] + S[4])
#define L_W      29376    // u32[5760]
#define L_V      35136    // u32[5376]
#define L_CV     40512    // f32[336]

__device__ __forceinline__ float fdot2w(h2 a, h2 b, float c) {
#if __has_builtin(__builtin_amdgcn_fdot2)
    return __builtin_amdgcn_fdot2(a, b, c, false);
#else
    return fmaf((float)a[0], (float)b[0], fmaf((float)a[1], (float)b[1], c));
#endif
}
__device__ __forceinline__ h2 pkrtz(float a, float b) {
    return __builtin_bit_cast(h2, __builtin_amdgcn_cvt_pkrtz(a, b));
}
#define BC(u)  __builtin_bit_cast(h2, (u))
#define BCU(v) __builtin_bit_cast(unsigned, (v))

// ---------------- prep: fold DCT/IDCT into Wp, Vt, cvec ----------------------
__global__ __launch_bounds__(256) void k_prep(const float* __restrict__ A,
                                              const float* __restrict__ B,
                                              const float* __restrict__ bias,
                                              float* __restrict__ Wp,
                                              float* __restrict__ Vt,
                                              float* __restrict__ cvec) {
    __shared__ float sbuf[IN_LEN * RANK];
    int blk = blockIdx.x;
    if (blk < 45) {
        for (int i = threadIdx.x; i < IN_LEN * RANK; i += 256) sbuf[i] = A[i];
        __syncthreads();
        int idx = blk * 256 + threadIdx.x;           // 45*256 == 11520
        int n = idx >> 5, r = idx & 31;
        int step = 2 * n + 1, m = 0;                 // k*(2n+1) mod 1440
        float sum = 0.f;
        for (int k = 0; k < IN_LEN; ++k) {
            float coef = (k == 0) ? 0.05270462766947299f    // 1/sqrt(360)
                                  : 0.07453559924999299f;   // 2/sqrt(720)
            float d = coef * cospif((float)m * (1.0f / 720.0f));
            sum = fmaf(d, sbuf[k * RANK + r], sum);
            m += step; if (m >= 1440) m -= 1440;
        }
        Wp[idx] = sum * 0.0019641855032960957f;      // (1/sqrt2)/360
    } else if (blk < 87) {
        for (int i = threadIdx.x; i < PRED_LEN * RANK; i += 256) {
            int r = i / PRED_LEN, k = i - r * PRED_LEN;
            sbuf[k * RANK + r] = B[i];               // B^T -> [k][r]
        }
        __syncthreads();
        int idx = (blk - 45) * 256 + threadIdx.x;    // 42*256 == 10752
        int n = idx >> 5, r = idx & 31;
        int step = 2 * n + 1, m = 0;                 // k*(2n+1) mod 1344
        float sum = 0.f;
        for (int k = 0; k < PRED_LEN; ++k) {
            float mk = cospif((float)m * (1.0f / 672.0f));
            if (k == 0) mk *= 0.5f;
            sum = fmaf(mk, sbuf[k * RANK + r], sum);
            m += step; if (m >= 1344) m -= 1344;
        }
        Vt[idx] = sum * (1.0f / 336.0f);
    } else {
        int n = (blk - 87) * 256 + threadIdx.x;
        if (n < PRED_LEN) {
            int step = 2 * n + 1, m = 0;
            float sum = 0.f;
            for (int k = 0; k < PRED_LEN; ++k) {
                float mk = cospif((float)m * (1.0f / 672.0f));
                if (k == 0) mk *= 0.5f;
                sum = fmaf(mk, bias[k], sum);
                m += step; if (m >= 1344) m -= 1344;
            }
            cvec[n] = sum * (1.0f / 336.0f);
        }
    }
}

// ---------------- pack fp32 weights into r-paired fp16 -----------------------
__global__ __launch_bounds__(256) void k_pack(const float* __restrict__ Wp,
                                              const float* __restrict__ Vt,
                                              unsigned* __restrict__ Wh,
                                              unsigned* __restrict__ Vh) {
    int idx = blockIdx.x * 256 + threadIdx.x;        // 44*256 = 11264 >= 11136
    if (idx < 5760) {                                // 360*16
        int n = idx >> 4, j = idx & 15;
        h2 v = pkrtz(Wp[n * RANK + 2 * j], Wp[n * RANK + 2 * j + 1]);
        Wh[idx] = BCU(v);
    } else if (idx < 5760 + 5376) {                  // 336*16
        int k = idx - 5760;
        int n = k >> 4, j = k & 15;
        h2 v = pkrtz(Vt[n * RANK + 2 * j], Vt[n * RANK + 2 * j + 1]);
        Vh[k] = BCU(v);
    }
}

// ---------------- fused main kernel ------------------------------------------
// One 512-thr block per batch (grid 256 -> 1 block/CU, 8 waves/CU).
// tid>>8 = K-half (rows 0-359 | 360-719); i=tid&255, i<216 active, 4 ch/thread.
// Every global access: full-row contiguous sweep, 16 B/lane (2x float2).
// fp16 packed accumulators (v_pk_fma_f16, r-paired) keep VGPR ~140 (no spill).
// Partials exchanged via LDS; phase 2 n-split (168 rows per half).
__global__ __launch_bounds__(512) void k_main(const float* __restrict__ x,
                                              const float* __restrict__ A,
                                              const unsigned* __restrict__ Wh,
                                              const unsigned* __restrict__ Vh,
                                              const float* __restrict__ cvec,
                                              float* __restrict__ out) {
    __shared__ unsigned ldsu[40848];                 // 163392 B
    const int tid = threadIdx.x;
    const int b = blockIdx.x;
    const int h = tid >> 8;
    const int i = tid & 255;
    const bool active = (i < 216);
    const int c0 = (i < 215) ? 4 * i : 858;          // last thread overlaps by 2 (dup writes)

    // ---- stage W, V, cvec ----
    for (int idx = tid; idx < 1440; idx += 512)
        ((uint4*)(ldsu + L_W))[idx] = ((const uint4*)Wh)[idx];
    for (int idx = tid; idx < 1344; idx += 512)
        ((uint4*)(ldsu + L_V))[idx] = ((const uint4*)Vh)[idx];
    for (int idx = tid; idx < 84; idx += 512)
        ((uint4*)(ldsu + L_CV))[idx] = ((const uint4*)cvec)[idx];
    __syncthreads();

    h2 acc0[16], acc1[16], acc2[16], acc3[16];
    #pragma unroll
    for (int j = 0; j < 16; ++j) {
        acc0[j] = pkrtz(0.f, 0.f); acc1[j] = pkrtz(0.f, 0.f);
        acc2[j] = pkrtz(0.f, 0.f); acc3[j] = pkrtz(0.f, 0.f);
    }
    float S0 = 0.f, S1 = 0.f, S2 = 0.f, S3 = 0.f;

    // ---- phase 1: partial t over this half's 180 n (360 rows) ----
    if (active) {
        const float* xp = x + (size_t)b * (SEQ_LEN * CHANNELS)
                            + (size_t)h * (IN_LEN * CHANNELS) + c0;
        float2 bA[4], bB[4];
        #define LOADN(BUF, NL) { const float* p_ = xp + (size_t)(2 * (NL)) * CHANNELS; \
            BUF[0] = *(const float2*)(p_);                 \
            BUF[1] = *(const float2*)(p_ + 2);             \
            BUF[2] = *(const float2*)(p_ + CHANNELS);      \
            BUF[3] = *(const float2*)(p_ + CHANNELS + 2); }

        #define BODY(BUF, NL) { \
            float p0 = BUF[0].x + BUF[2].x; \
            float p1 = BUF[0].y + BUF[2].y; \
            float p2 = BUF[1].x + BUF[3].x; \
            float p3 = BUF[1].y + BUF[3].y; \
            S0 += p0; S1 += p1; S2 += p2; S3 += p3; \
            h2 P0 = pkrtz(p0, p0), P1 = pkrtz(p1, p1); \
            h2 P2 = pkrtz(p2, p2), P3 = pkrtz(p3, p3); \
            const uint4* wr = (const uint4*)(ldsu + L_W) + ((NL) + 180 * h) * 4; \
            _Pragma("unroll") \
            for (int q_ = 0; q_ < 4; ++q_) { \
                uint4 wv = wr[q_]; \
                h2 w0 = BC(wv.x), w1 = BC(wv.y), w2 = BC(wv.z), w3 = BC(wv.w); \
                acc0[4*q_+0] = w0 * P0 + acc0[4*q_+0]; \
                acc1[4*q_+0] = w0 * P1 + acc1[4*q_+0]; \
                acc2[4*q_+0] = w0 * P2 + acc2[4*q_+0]; \
                acc3[4*q_+0] = w0 * P3 + acc3[4*q_+0]; \
                acc0[4*q_+1] = w1 * P0 + acc0[4*q_+1]; \
                acc1[4*q_+1] = w1 * P1 + acc1[4*q_+1]; \
                acc2[4*q_+1] = w1 * P2 + acc2[4*q_+1]; \
                acc3[4*q_+1] = w1 * P3 + acc3[4*q_+1]; \
                acc0[4*q_+2] = w2 * P0 + acc0[4*q_+2]; \
                acc1[4*q_+2] = w2 * P1 + acc1[4*q_+2]; \
                acc2[4*q_+2] = w2 * P2 + acc2[4*q_+2]; \
                acc3[4*q_+2] = w2 * P3 + acc3[4*q_+2]; \
                acc0[4*q_+3] = w3 * P0 + acc0[4*q_+3]; \
                acc1[4*q_+3] = w3 * P1 + acc1[4*q_+3]; \
                acc2[4*q_+3] = w3 * P2 + acc2[4*q_+3]; \
                acc3[4*q_+3] = w3 * P3 + acc3[4*q_+3]; \
            } }

        LOADN(bA, 0)
        for (int n = 0; n < 180; n += 2) {
            LOADN(bB, n + 1)
            BODY(bA, n)
            if (n + 2 < 180) LOADN(bA, n + 2)
            BODY(bB, n + 1)
        }
        #undef BODY
        #undef LOADN
    }

    // ---- write partial record (16B-aligned: 272 B/slot) ----
    if (active) {
        uint4* rec = (uint4*)(ldsu + (i + 216 * h) * 68);
        #pragma unroll
        for (int q = 0; q < 4; ++q) {
            uint4 v;
            v.x = BCU(acc0[4*q+0]); v.y = BCU(acc0[4*q+1]);
            v.z = BCU(acc0[4*q+2]); v.w = BCU(acc0[4*q+3]);
            rec[q] = v;
            v.x = BCU(acc1[4*q+0]); v.y = BCU(acc1[4*q+1]);
            v.z = BCU(acc1[4*q+2]); v.w = BCU(acc1[4*q+3]);
            rec[4 + q] = v;
            v.x = BCU(acc2[4*q+0]); v.y = BCU(acc2[4*q+1]);
            v.z = BCU(acc2[4*q+2]); v.w = BCU(acc2[4*q+3]);
            rec[8 + q] = v;
            v.x = BCU(acc3[4*q+0]); v.y = BCU(acc3[4*q+1]);
            v.z = BCU(acc3[4*q+2]); v.w = BCU(acc3[4*q+3]);
            rec[12 + q] = v;
        }
        uint4 sv;
        sv.x = __float_as_uint(S0); sv.y = __float_as_uint(S1);
        sv.z = __float_as_uint(S2); sv.w = __float_as_uint(S3);
        rec[16] = sv;
    }
    __syncthreads();

    float mean0 = 0.f, mean1 = 0.f, mean2 = 0.f, mean3 = 0.f;
    if (active) {
        // ---- combine partner half ----
        const uint4* pr = (const uint4*)(ldsu + (i + 216 * (1 - h)) * 68);
        #pragma unroll
        for (int q = 0; q < 4; ++q) {
            uint4 v = pr[q];
            acc0[4*q+0] = acc0[4*q+0] + BC(v.x); acc0[4*q+1] = acc0[4*q+1] + BC(v.y);
            acc0[4*q+2] = acc0[4*q+2] + BC(v.z); acc0[4*q+3] = acc0[4*q+3] + BC(v.w);
            v = pr[4 + q];
            acc1[4*q+0] = acc1[4*q+0] + BC(v.x); acc1[4*q+1] = acc1[4*q+1] + BC(v.y);
            acc1[4*q+2] = acc1[4*q+2] + BC(v.z); acc1[4*q+3] = acc1[4*q+3] + BC(v.w);
            v = pr[8 + q];
            acc2[4*q+0] = acc2[4*q+0] + BC(v.x); acc2[4*q+1] = acc2[4*q+1] + BC(v.y);
            acc2[4*q+2] = acc2[4*q+2] + BC(v.z); acc2[4*q+3] = acc2[4*q+3] + BC(v.w);
            v = pr[12 + q];
            acc3[4*q+0] = acc3[4*q+0] + BC(v.x); acc3[4*q+1] = acc3[4*q+1] + BC(v.y);
            acc3[4*q+2] = acc3[4*q+2] + BC(v.z); acc3[4*q+3] = acc3[4*q+3] + BC(v.w);
        }
        uint4 sv = pr[16];
        S0 += __uint_as_float(sv.x); S1 += __uint_as_float(sv.y);
        S2 += __uint_as_float(sv.z); S3 += __uint_as_float(sv.w);

        // ---- finalize: t[r] -= S*(1/360)*A[0][r]/sqrt(720) ----
        const float kc = (1.0f / 360.0f) * 0.037267799624996496f;
        float g0 = -S0 * kc, g1 = -S1 * kc, g2 = -S2 * kc, g3 = -S3 * kc;
        h2 G0 = pkrtz(g0, g0), G1 = pkrtz(g1, g1), G2 = pkrtz(g2, g2), G3 = pkrtz(g3, g3);
        #pragma unroll
        for (int q = 0; q < 8; ++q) {
            float4 a4 = ((const float4*)A)[q];       // A[0][0..31], uniform, L2-hot
            h2 aa = pkrtz(a4.x, a4.y), ab = pkrtz(a4.z, a4.w);
            acc0[2*q]   = aa * G0 + acc0[2*q];   acc0[2*q+1] = ab * G0 + acc0[2*q+1];
            acc1[2*q]   = aa * G1 + acc1[2*q];   acc1[2*q+1] = ab * G1 + acc1[2*q+1];
            acc2[2*q]   = aa * G2 + acc2[2*q];   acc2[2*q+1] = ab * G2 + acc2[2*q+1];
            acc3[2*q]   = aa * G3 + acc3[2*q];   acc3[2*q+1] = ab * G3 + acc3[2*q+1];
        }
        mean0 = S0 * (1.0f / 720.0f); mean1 = S1 * (1.0f / 720.0f);
        mean2 = S2 * (1.0f / 720.0f); mean3 = S3 * (1.0f / 720.0f);

        // ---- phase 2: this half's 168 output rows ----
        float* op = out + (size_t)b * (PRED_LEN * CHANNELS)
                        + (size_t)(168 * h) * CHANNELS + c0;
        for (int nl = 0; nl < 168; ++nl) {
            const int n = 168 * h + nl;
            const uint4* vr = (const uint4*)(ldsu + L_V) + n * 4;
            float o0 = 0.f, o1 = 0.f, o2 = 0.f, o3 = 0.f;
            float e0 = 0.f, e1 = 0.f, e2 = 0.f, e3 = 0.f;
            #pragma unroll
            for (int q = 0; q < 4; ++q) {
                uint4 v = vr[q];
                h2 v0 = BC(v.x), v1 = BC(v.y), v2 = BC(v.z), v3 = BC(v.w);
                o0 = fdot2w(acc0[4*q+0], v0, o0); e0 = fdot2w(acc0[4*q+1], v1, e0);
                o1 = fdot2w(acc1[4*q+0], v0, o1); e1 = fdot2w(acc1[4*q+1], v1, e1);
                o2 = fdot2w(acc2[4*q+0], v0, o2); e2 = fdot2w(acc2[4*q+1], v1, e2);
                o3 = fdot2w(acc3[4*q+0], v0, o3); e3 = fdot2w(acc3[4*q+1], v1, e3);
                o0 = fdot2w(acc0[4*q+2], v2, o0); e0 = fdot2w(acc0[4*q+3], v3, e0);
                o1 = fdot2w(acc1[4*q+2], v2, o1); e1 = fdot2w(acc1[4*q+3], v3, e1);
                o2 = fdot2w(acc2[4*q+2], v2, o2); e2 = fdot2w(acc2[4*q+3], v3, e2);
                o3 = fdot2w(acc3[4*q+2], v2, o3); e3 = fdot2w(acc3[4*q+3], v3, e3);
            }
            float cvn = ((const float*)(ldsu + L_CV))[n];
            float2 w0, w1;
            w0.x = (o0 + e0) + cvn + mean0;
            w0.y = (o1 + e1) + cvn + mean1;
            w1.x = (o2 + e2) + cvn + mean2;
            w1.y = (o3 + e3) + cvn + mean3;
            *(float2*)(op)     = w0;
            *(float2*)(op + 2) = w1;
            op += CHANNELS;
        }
    }
}

// ---------------- launcher ---------------------------------------------------

extern "C" void kernel_launch(void* const* d_in, const int* in_sizes, int n_in,
                              void* d_out, int out_size, void* d_ws, size_t ws_size,
                              hipStream_t stream) {
    (void)in_sizes; (void)n_in; (void)out_size; (void)ws_size;
    const float* x    = (const float*)d_in[0];
    const float* A    = (const float*)d_in[1];
    const float* B    = (const float*)d_in[2];
    const float* bias = (const float*)d_in[3];
    float* out = (float*)d_out;
    float* ws  = (float*)d_ws;

    float*    Wp   = ws + WS_WP;
    float*    Vt   = ws + WS_VT;
    float*    cvec = ws + WS_CVEC;
    unsigned* Wh   = (unsigned*)(ws + WS_WH);
    unsigned* Vh   = (unsigned*)(ws + WS_VH);

    k_prep<<<dim3(89), dim3(256), 0, stream>>>(A, B, bias, Wp, Vt, cvec);
    k_pack<<<dim3(44), dim3(256), 0, stream>>>(Wp, Vt, Wh, Vh);
    k_main<<<dim3(BATCH), dim3(512), 0, stream>>>(x, A, Wh, Vh, cvec, out);
}